// Round 6
// baseline (97.557 us; speedup 1.0000x reference)
//
#include <hip/hip_runtime.h>

// 10-qubit circuit: 10x Rot(phi,theta,omega) + CNOT ring + <X>,<Y>,<Z> on wire 0.
//
// Circuit = D_omega * RY_layer * D_phi on a REAL input. State = two real vectors
// evolved by the same real RY layer.
//
// R12: ONE CODE COPY, TWO EXECUTIONS (I-cache theory).
// Evidence trail: R9 REP=8 diagnostic -> steady-state rep = 14.6us @ 88%
// VALUBusy (issue floor), but rep 1 alone ~32us @ ~47% busy. The first-pass
// penalty is insensitive to wave count (R11), DS vs permlane (R7), packing
// (R10). Theory: the ~18-20KB fully-unrolled body misses L1I continuously on
// its single cold pass (all waves in lockstep; ~300 lines x ~150cy from L2);
// REP>=2 re-executes warm code -> full issue rate. R11 regressed slightly
// because its lambda inlined TWICE (~40KB, zero I-reuse).
// Fix: identical work distribution to R11 (2 states/wave, 1024 blocks), but
// the state body exists ONCE, inside a '#pragma unroll 1' loop; operands
// selected per-iteration via cndmask. Iteration 2 runs L1I-warm.
// Prediction: kernel ~38 -> ~26-29us, dur_us ~73-77. If neutral, I-cache
// theory is dead -> next: s_memtime phase-timing build.
//
// Layout (validated R4/R5): lane holds 16 complex amps, slots s = h*4+q,
// idx = h*256 + lane*4 + q.
//   slot bit0=wire9, bit1=wire8, bit2=wire1, bit3=wire0  (in-register gates)
//   lane bit l = wire 7-l                                 (cross-lane gates)
// Measurement partner idx^0x300 = slot^12 (in-register, no shuffles).
// Cross-lane masks 1,2,4,8 via DPP (VALU); 16,32 via permlane_swap (VALU).
// Scalar form (R10: cycle-neutral vs v_pk, DPP fusable into v_fmac_f32).

typedef unsigned int v2u __attribute__((ext_vector_type(2)));

template <int CTRL>
__device__ __forceinline__ float dppf(float x) {
    return __int_as_float(__builtin_amdgcn_update_dpp(
        __float_as_int(x), __float_as_int(x), CTRL, 0xF, 0xF, true));
}

template <int MASK>
__device__ __forceinline__ float lxor(float x) {
    if constexpr (MASK == 1)  return dppf<0xB1>(x);                   // quad_perm [1,0,3,2]
    else if constexpr (MASK == 2)  return dppf<0x4E>(x);              // quad_perm [2,3,0,1]
    else if constexpr (MASK == 4)  return dppf<0x141>(dppf<0x1B>(x)); // half_mirror o xor3
    else if constexpr (MASK == 8)  return dppf<0x128>(x);             // row_ror:8
    else if constexpr (MASK == 16)
        return __int_as_float(__builtin_amdgcn_ds_swizzle(__float_as_int(x), 0x401F));
    else return __shfl_xor(x, MASK, 64);
}

// partner value x[lane^MASK]; hi = (lane & MASK) != 0 (only used for 16/32)
template <int MASK>
__device__ __forceinline__ float xpartner(float x, bool hi) {
    if constexpr (MASK == 16) {
#if __has_builtin(__builtin_amdgcn_permlane16_swap)
        v2u r = __builtin_amdgcn_permlane16_swap(__float_as_uint(x), __float_as_uint(x),
                                                 false, false);
        return __uint_as_float(hi ? r.x : r.y);
#else
        (void)hi;
        return lxor<16>(x);
#endif
    } else if constexpr (MASK == 32) {
#if __has_builtin(__builtin_amdgcn_permlane32_swap)
        v2u r = __builtin_amdgcn_permlane32_swap(__float_as_uint(x), __float_as_uint(x),
                                                 false, false);
        return __uint_as_float(hi ? r.x : r.y);
#else
        (void)hi;
        return lxor<32>(x);
#endif
    } else {
        (void)hi;
        return lxor<MASK>(x);
    }
}

#define RLF(v, l) __int_as_float(__builtin_amdgcn_readlane(__float_as_int(v), (l)))

// RY pair rotation, scalar: a0' = c*a0 - s*a1 ; a1' = c*a1 + s*a0
__device__ __forceinline__ void rgate(float (&ax)[16], float (&ay)[16],
                                      int bit, float c, float s) {
#pragma unroll
    for (int s0 = 0; s0 < 16; s0++) {
        if (s0 & bit) continue;
        int s1 = s0 | bit;
        float a0x = ax[s0], a1x = ax[s1];
        float a0y = ay[s0], a1y = ay[s1];
        ax[s0] = __builtin_fmaf(-s, a1x, c * a0x);
        ax[s1] = __builtin_fmaf( s, a0x, c * a1x);
        ay[s0] = __builtin_fmaf(-s, a1y, c * a0y);
        ay[s1] = __builtin_fmaf( s, a0y, c * a1y);
    }
}

// cross-lane RY: a' = c*a + ss*partner(a), v_fmac-friendly form
template <int MASK>
__device__ __forceinline__ void xgate(float (&ax)[16], float (&ay)[16],
                                      float c, float ss, bool hi) {
#pragma unroll
    for (int r = 0; r < 16; r++) {
        float px = xpartner<MASK>(ax[r], hi);
        float py = xpartner<MASK>(ay[r], hi);
        float tx = c * ax[r];
        float ty = c * ay[r];
        ax[r] = __builtin_fmaf(px, ss, tx);
        ay[r] = __builtin_fmaf(py, ss, ty);
    }
}

__global__ __launch_bounds__(256, 4) void qk_sim(const float* __restrict__ x,
                                                 const float* __restrict__ w,
                                                 float* __restrict__ out,
                                                 int nstates) {
    int wave = (int)((blockIdx.x * blockDim.x + threadIdx.x) >> 6);
    int lane = threadIdx.x & 63;

    int sA = 2 * wave;      // this wave handles states sA and sA+1

    // ---- prefetch BOTH states' rows up front (B hides under A's compute) ----
    const float4* rowA = (const float4*)(x + (size_t)sA * 1024);
    float4 va0 = rowA[0 * 64 + lane];
    float4 va1 = rowA[1 * 64 + lane];
    float4 va2 = rowA[2 * 64 + lane];
    float4 va3 = rowA[3 * 64 + lane];
    float4 vb0 = rowA[4 * 64 + lane];   // state sA+1 is the next 1024 floats
    float4 vb1 = rowA[5 * 64 + lane];
    float4 vb2 = rowA[6 * 64 + lane];
    float4 vb3 = rowA[7 * 64 + lane];

    // ---- theta cos/sin: lanes 0..9 compute, broadcast via v_readlane ----
    int wi = (lane < 10) ? lane : 0;
    float thh = 0.5f * w[3 * wi + 1];
    float vc = __cosf(thh), vs = __sinf(thh);
    float c0 = RLF(vc, 0), s0 = RLF(vs, 0);
    float c1 = RLF(vc, 1), s1 = RLF(vs, 1);
    float c2 = RLF(vc, 2), s2 = RLF(vs, 2);
    float c3 = RLF(vc, 3), s3 = RLF(vs, 3);
    float c4 = RLF(vc, 4), s4 = RLF(vs, 4);
    float c5 = RLF(vc, 5), s5 = RLF(vs, 5);
    float c6 = RLF(vc, 6), s6 = RLF(vs, 6);
    float c7 = RLF(vc, 7), s7 = RLF(vs, 7);
    float c8 = RLF(vc, 8), s8 = RLF(vs, 8);
    float c9 = RLF(vc, 9), s9 = RLF(vs, 9);

    // ---- omega fold (uniform): d0 = w0+w1 omegas (h=0), d1 = w0-w1 (h=1) ----
    float om0 = w[2], om1 = w[5];
    float cD0 = __cosf(om0 + om1), sD0 = __sinf(om0 + om1);
    float cD1 = __cosf(om0 - om1), sD1 = __sinf(om0 - om1);

    // ---- phase angles: alpha(idx) = aL(lane) + aH(h) + aQ(q) ----
    float aL = 0.f;
    if (lane & 1)  aL += w[21];
    if (lane & 2)  aL += w[18];
    if (lane & 4)  aL += w[15];
    if (lane & 8)  aL += w[12];
    if (lane & 16) aL += w[9];
    if (lane & 32) aL += w[6];
    float pH = w[0], pHb = w[3];   // wire0, wire1
    float pQ = w[24], pQb = w[27]; // wire8, wire9
    float aH[4] = {0.f, pHb, pH, pH + pHb};
    float aQ[4] = {0.f, pQb, pQ, pQ + pQb};

    bool h16 = (lane & 16) != 0;
    bool h32 = (lane & 32) != 0;
    float psgn = (__popc(lane) & 1) ? -1.f : 1.f;

    // ---- TWO executions of ONE code copy: '#pragma unroll 1' is the point ----
#pragma unroll 1
    for (int t = 0; t < 2; ++t) {
        // operand select (v_cndmask), keeps a single machine-code body
        float4 u0, u1, u2, u3;
        u0.x = t ? vb0.x : va0.x; u0.y = t ? vb0.y : va0.y;
        u0.z = t ? vb0.z : va0.z; u0.w = t ? vb0.w : va0.w;
        u1.x = t ? vb1.x : va1.x; u1.y = t ? vb1.y : va1.y;
        u1.z = t ? vb1.z : va1.z; u1.w = t ? vb1.w : va1.w;
        u2.x = t ? vb2.x : va2.x; u2.y = t ? vb2.y : va2.y;
        u2.z = t ? vb2.z : va2.z; u2.w = t ? vb2.w : va2.w;
        u3.x = t ? vb3.x : va3.x; u3.y = t ? vb3.y : va3.y;
        u3.z = t ? vb3.z : va3.z; u3.w = t ? vb3.w : va3.w;

        // D_phi: amp[s] = x[idx] * e^{i alpha}
        float ax[16], ay[16];
#pragma unroll
        for (int h = 0; h < 4; h++) {
            const float4& v = (h == 0) ? u0 : (h == 1) ? u1 : (h == 2) ? u2 : u3;
            float base = aL + aH[h];
            float xv[4] = {v.x, v.y, v.z, v.w};
#pragma unroll
            for (int q = 0; q < 4; q++) {
                float a = base + aQ[q];
                ax[h * 4 + q] = xv[q] * __cosf(a);
                ay[h * 4 + q] = xv[q] * __sinf(a);
            }
        }

        // in-register RY: slot bit0=wire9, bit1=wire8, bit2=wire1, bit3=wire0
        rgate(ax, ay, 1, c9, s9);
        rgate(ax, ay, 2, c8, s8);
        rgate(ax, ay, 4, c1, s1);
        rgate(ax, ay, 8, c0, s0);

        // cross-lane RY: lane bit l -> wire 7-l
        xgate<1> (ax, ay, c7, (lane & 1) ? s7 : -s7, false);
        xgate<2> (ax, ay, c6, (lane & 2) ? s6 : -s6, false);
        xgate<4> (ax, ay, c5, (lane & 4) ? s5 : -s5, false);
        xgate<8> (ax, ay, c4, (lane & 8) ? s4 : -s4, false);
        xgate<16>(ax, ay, c3, h16 ? s3 : -s3, h16);
        xgate<32>(ax, ay, c2, h32 ? s2 : -s2, h32);

        // measurement: CNOT ring + D_omega folded; partner = slot^12
        float ex2 = 0.f, ey2 = 0.f, ez0 = 0.f;
#pragma unroll
        for (int h = 0; h < 2; h++) {
            float cD = h ? cD1 : cD0;
            float sD = h ? sD1 : sD0;
#pragma unroll
            for (int q = 0; q < 4; q++) {
                int s  = h * 4 + q;
                int sp = s ^ 12;
                float mx = ax[s],  my = ay[s];
                float px = ax[sp], py = ay[sp];
                float cr = __builtin_fmaf(mx, px, my * py);    // Re(conj(m)*p)
                float ci = __builtin_fmaf(mx, py, -(my * px)); // Im(conj(m)*p)
                ex2 = __builtin_fmaf(cD, cr, ex2);
                ex2 = __builtin_fmaf(-sD, ci, ex2);
                float t2 = __builtin_fmaf(cD, ci, sD * cr);
                if ((h ^ (__popc(q) & 1)) & 1) ey2 -= t2; else ey2 += t2;
            }
        }
#pragma unroll
        for (int s = 0; s < 16; s++) {
            float n = __builtin_fmaf(ax[s], ax[s], ay[s] * ay[s]);
            if ((((s >> 2) & 1) ^ (__popc(s & 3) & 1)) & 1) ez0 -= n; else ez0 += n;
        }
        float ex = 2.f * ex2;
        float ey = 2.f * psgn * ey2;
        float ez = psgn * ez0;

        // wave reduction: DPP for 1,2,4,8; permlane_swap for 16,32
#define RED(M, HI) { ex += xpartner<M>(ex, HI); ey += xpartner<M>(ey, HI); \
                     ez += xpartner<M>(ez, HI); }
        RED(1, false) RED(2, false) RED(4, false) RED(8, false) RED(16, h16) RED(32, h32)
#undef RED

        if (lane == 0) {
            float* o = out + 3 * (size_t)(sA + t);
            o[0] = ex; o[1] = ey; o[2] = ez;
        }
    }
}

extern "C" void kernel_launch(void* const* d_in, const int* in_sizes, int n_in,
                              void* d_out, int out_size, void* d_ws, size_t ws_size,
                              hipStream_t stream) {
    const float* patch   = (const float*)d_in[0];
    const float* weights = (const float*)d_in[1];
    float* out = (float*)d_out;

    int nstates = in_sizes[0] / 1024;  // 8192

    // 2 states per wave, 4 waves per block -> 8 states per block
    int nblocks = nstates / 8;  // 1024 blocks
    qk_sim<<<nblocks, 256, 0, stream>>>(patch, weights, out, nstates);
}

// Round 8
// 90.069 us; speedup vs baseline: 1.0831x; 1.0831x over previous
//
#include <hip/hip_runtime.h>

// 10-qubit circuit: 10x Rot(phi,theta,omega) + CNOT ring + <X>,<Y>,<Z> on wire 0.
//
// R14: R13 retry -- nontemporal loads via NATIVE vector type.
// (__builtin_nontemporal_load rejects HIP_vector_type<float,4>*; it requires
// scalar/pointer/native-vector element types. Use ext_vector_type(4) floats.)
//
// Ledger: dur_us = ~43us harness poison-fill + ~41us kernel. REP=8 (R9):
// marginal pass 14.6us @ 88% VALUBusy (issue floor, memory idle). The ~26us
// first-pass residue is invariant to DS-vs-VALU (R7), packing (R10),
// states/wave + wg count (R11), code-copy count (R12) -- it follows DATA
// first-touch (warm only when re-touching the same bytes, R9 reps 2-8).
// Test: x is read exactly once -> nontemporal 'nt' load bypasses cache
// allocation against the freshly-poisoned hierarchy. If the residue is
// allocation/eviction-related this helps; if translation-walk, neutral.
//
// Layout (validated R4/R5): one wave per state; lane holds 16 complex amps,
// slots s = h*4+q, idx = h*256 + lane*4 + q.
//   slot bit0=wire9, bit1=wire8, bit2=wire1, bit3=wire0  (in-register gates)
//   lane bit l = wire 7-l                                 (cross-lane gates)
// Measurement partner idx^0x300 = slot^12 (in-register, no shuffles).
// Cross-lane masks 1,2,4,8 via DPP (VALU); 16,32 via permlane_swap (VALU).
// Scalar form (R10: cycle-neutral vs v_pk, DPP fusable into v_fmac_f32).

typedef unsigned int v2u __attribute__((ext_vector_type(2)));
typedef float v4f __attribute__((ext_vector_type(4)));

template <int CTRL>
__device__ __forceinline__ float dppf(float x) {
    return __int_as_float(__builtin_amdgcn_update_dpp(
        __float_as_int(x), __float_as_int(x), CTRL, 0xF, 0xF, true));
}

template <int MASK>
__device__ __forceinline__ float lxor(float x) {
    if constexpr (MASK == 1)  return dppf<0xB1>(x);                   // quad_perm [1,0,3,2]
    else if constexpr (MASK == 2)  return dppf<0x4E>(x);              // quad_perm [2,3,0,1]
    else if constexpr (MASK == 4)  return dppf<0x141>(dppf<0x1B>(x)); // half_mirror o xor3
    else if constexpr (MASK == 8)  return dppf<0x128>(x);             // row_ror:8
    else if constexpr (MASK == 16)
        return __int_as_float(__builtin_amdgcn_ds_swizzle(__float_as_int(x), 0x401F));
    else return __shfl_xor(x, MASK, 64);
}

// partner value x[lane^MASK]; hi = (lane & MASK) != 0 (only used for 16/32)
template <int MASK>
__device__ __forceinline__ float xpartner(float x, bool hi) {
    if constexpr (MASK == 16) {
#if __has_builtin(__builtin_amdgcn_permlane16_swap)
        v2u r = __builtin_amdgcn_permlane16_swap(__float_as_uint(x), __float_as_uint(x),
                                                 false, false);
        return __uint_as_float(hi ? r.x : r.y);
#else
        (void)hi;
        return lxor<16>(x);
#endif
    } else if constexpr (MASK == 32) {
#if __has_builtin(__builtin_amdgcn_permlane32_swap)
        v2u r = __builtin_amdgcn_permlane32_swap(__float_as_uint(x), __float_as_uint(x),
                                                 false, false);
        return __uint_as_float(hi ? r.x : r.y);
#else
        (void)hi;
        return lxor<32>(x);
#endif
    } else {
        (void)hi;
        return lxor<MASK>(x);
    }
}

#define RLF(v, l) __int_as_float(__builtin_amdgcn_readlane(__float_as_int(v), (l)))

// RY pair rotation, scalar: a0' = c*a0 - s*a1 ; a1' = c*a1 + s*a0
__device__ __forceinline__ void rgate(float (&ax)[16], float (&ay)[16],
                                      int bit, float c, float s) {
#pragma unroll
    for (int s0 = 0; s0 < 16; s0++) {
        if (s0 & bit) continue;
        int s1 = s0 | bit;
        float a0x = ax[s0], a1x = ax[s1];
        float a0y = ay[s0], a1y = ay[s1];
        ax[s0] = __builtin_fmaf(-s, a1x, c * a0x);
        ax[s1] = __builtin_fmaf( s, a0x, c * a1x);
        ay[s0] = __builtin_fmaf(-s, a1y, c * a0y);
        ay[s1] = __builtin_fmaf( s, a0y, c * a1y);
    }
}

// cross-lane RY: a' = c*a + ss*partner(a), v_fmac-friendly form
template <int MASK>
__device__ __forceinline__ void xgate(float (&ax)[16], float (&ay)[16],
                                      float c, float ss, bool hi) {
#pragma unroll
    for (int r = 0; r < 16; r++) {
        float px = xpartner<MASK>(ax[r], hi);
        float py = xpartner<MASK>(ay[r], hi);
        float tx = c * ax[r];
        float ty = c * ay[r];
        ax[r] = __builtin_fmaf(px, ss, tx);
        ay[r] = __builtin_fmaf(py, ss, ty);
    }
}

__global__ __launch_bounds__(256, 8) void qk_sim(const float* __restrict__ x,
                                                 const float* __restrict__ w,
                                                 float* __restrict__ out,
                                                 int nstates) {
    int wave = (int)((blockIdx.x * blockDim.x + threadIdx.x) >> 6);
    int lane = threadIdx.x & 63;

    // ---- issue the 4 state loads FIRST, nontemporal (read-once stream) ----
    const v4f* rowx = (const v4f*)(x + (size_t)wave * 1024);
    v4f vv0 = __builtin_nontemporal_load(&rowx[0 * 64 + lane]);
    v4f vv1 = __builtin_nontemporal_load(&rowx[1 * 64 + lane]);
    v4f vv2 = __builtin_nontemporal_load(&rowx[2 * 64 + lane]);
    v4f vv3 = __builtin_nontemporal_load(&rowx[3 * 64 + lane]);

    // ---- theta cos/sin: lanes 0..9 compute, broadcast via v_readlane ----
    int wi = (lane < 10) ? lane : 0;
    float thh = 0.5f * w[3 * wi + 1];
    float vc = __cosf(thh), vs = __sinf(thh);
    float c0 = RLF(vc, 0), s0 = RLF(vs, 0);
    float c1 = RLF(vc, 1), s1 = RLF(vs, 1);
    float c2 = RLF(vc, 2), s2 = RLF(vs, 2);
    float c3 = RLF(vc, 3), s3 = RLF(vs, 3);
    float c4 = RLF(vc, 4), s4 = RLF(vs, 4);
    float c5 = RLF(vc, 5), s5 = RLF(vs, 5);
    float c6 = RLF(vc, 6), s6 = RLF(vs, 6);
    float c7 = RLF(vc, 7), s7 = RLF(vs, 7);
    float c8 = RLF(vc, 8), s8 = RLF(vs, 8);
    float c9 = RLF(vc, 9), s9 = RLF(vs, 9);

    // ---- omega fold (uniform): d0 = w0+w1 omegas (h=0), d1 = w0-w1 (h=1) ----
    float om0 = w[2], om1 = w[5];
    float cD0 = __cosf(om0 + om1), sD0 = __sinf(om0 + om1);
    float cD1 = __cosf(om0 - om1), sD1 = __sinf(om0 - om1);

    // ---- phase angles: alpha(idx) = aL(lane) + aH(h) + aQ(q) ----
    float aL = 0.f;
    if (lane & 1)  aL += w[21];
    if (lane & 2)  aL += w[18];
    if (lane & 4)  aL += w[15];
    if (lane & 8)  aL += w[12];
    if (lane & 16) aL += w[9];
    if (lane & 32) aL += w[6];
    float pH = w[0], pHb = w[3];   // wire0, wire1
    float pQ = w[24], pQb = w[27]; // wire8, wire9
    float aH[4] = {0.f, pHb, pH, pH + pHb};
    float aQ[4] = {0.f, pQb, pQ, pQ + pQb};

    // ---- D_phi: amp[s] = x[idx] * e^{i alpha}, scalar components ----
    float ax[16], ay[16];
#pragma unroll
    for (int h = 0; h < 4; h++) {
        const v4f& v = (h == 0) ? vv0 : (h == 1) ? vv1 : (h == 2) ? vv2 : vv3;
        float base = aL + aH[h];
        float xv[4] = {v.x, v.y, v.z, v.w};
#pragma unroll
        for (int q = 0; q < 4; q++) {
            float a = base + aQ[q];
            ax[h * 4 + q] = xv[q] * __cosf(a);
            ay[h * 4 + q] = xv[q] * __sinf(a);
        }
    }

    // ---- in-register RY: slot bit0=wire9, bit1=wire8, bit2=wire1, bit3=wire0 ----
    rgate(ax, ay, 1, c9, s9);
    rgate(ax, ay, 2, c8, s8);
    rgate(ax, ay, 4, c1, s1);
    rgate(ax, ay, 8, c0, s0);

    // ---- cross-lane RY: lane bit l -> wire 7-l ----
    bool h16 = (lane & 16) != 0;
    bool h32 = (lane & 32) != 0;
    xgate<1> (ax, ay, c7, (lane & 1) ? s7 : -s7, false);
    xgate<2> (ax, ay, c6, (lane & 2) ? s6 : -s6, false);
    xgate<4> (ax, ay, c5, (lane & 4) ? s5 : -s5, false);
    xgate<8> (ax, ay, c4, (lane & 8) ? s4 : -s4, false);
    xgate<16>(ax, ay, c3, h16 ? s3 : -s3, h16);
    xgate<32>(ax, ay, c2, h32 ? s2 : -s2, h32);

    // ---- measurement: CNOT ring + D_omega folded; partner = slot^12 ----
    float ex2 = 0.f, ey2 = 0.f, ez0 = 0.f;
#pragma unroll
    for (int h = 0; h < 2; h++) {
        float cD = h ? cD1 : cD0;
        float sD = h ? sD1 : sD0;
#pragma unroll
        for (int q = 0; q < 4; q++) {
            int s  = h * 4 + q;
            int sp = s ^ 12;
            float mx = ax[s],  my = ay[s];
            float px = ax[sp], py = ay[sp];
            float cr = __builtin_fmaf(mx, px, my * py);    // Re(conj(m)*p)
            float ci = __builtin_fmaf(mx, py, -(my * px)); // Im(conj(m)*p)
            ex2 = __builtin_fmaf(cD, cr, ex2);
            ex2 = __builtin_fmaf(-sD, ci, ex2);
            float t = __builtin_fmaf(cD, ci, sD * cr);
            if ((h ^ (__popc(q) & 1)) & 1) ey2 -= t; else ey2 += t;
        }
    }
#pragma unroll
    for (int s = 0; s < 16; s++) {
        float n = __builtin_fmaf(ax[s], ax[s], ay[s] * ay[s]);
        if ((((s >> 2) & 1) ^ (__popc(s & 3) & 1)) & 1) ez0 -= n; else ez0 += n;
    }
    float psgn = (__popc(lane) & 1) ? -1.f : 1.f;
    float ex = 2.f * ex2;
    float ey = 2.f * psgn * ey2;
    float ez = psgn * ez0;

    // ---- wave reduction: DPP for 1,2,4,8; permlane_swap for 16,32 ----
#define RED(M, HI) { ex += xpartner<M>(ex, HI); ey += xpartner<M>(ey, HI); \
                     ez += xpartner<M>(ez, HI); }
    RED(1, false) RED(2, false) RED(4, false) RED(8, false) RED(16, h16) RED(32, h32)
#undef RED

    if (lane == 0) {
        float* o = out + 3 * (size_t)wave;
        o[0] = ex; o[1] = ey; o[2] = ez;
    }
}

extern "C" void kernel_launch(void* const* d_in, const int* in_sizes, int n_in,
                              void* d_out, int out_size, void* d_ws, size_t ws_size,
                              hipStream_t stream) {
    const float* patch   = (const float*)d_in[0];
    const float* weights = (const float*)d_in[1];
    float* out = (float*)d_out;

    int nstates = in_sizes[0] / 1024;  // 8192

    int nblocks = nstates / 4;  // 4 waves (256 threads) per block, grid exact
    qk_sim<<<nblocks, 256, 0, stream>>>(patch, weights, out, nstates);
}

// Round 9
// 86.668 us; speedup vs baseline: 1.1256x; 1.0392x over previous
//
#include <hip/hip_runtime.h>

// 10-qubit circuit: 10x Rot(phi,theta,omega) + CNOT ring + <X>,<Y>,<Z> on wire 0.
//
// R15: TRANS-ELIMINATION (phasor factorization).
// Audit of R9's REP=8 counters: steady-state = 4620 issue-cyc/wave-state vs
// ~2500 static VALU model. Gap ~= 32 D_phi sin/cos if v_sin/v_cos_f32 occupy
// ~64 cyc/wave64 op (near 1 lane/cyc) instead of assumed quarter-rate.
// Fix: alpha(idx) = aL(lane) + aHQ(slot) with aHQ LANE-UNIFORM, so
//   e^{i alpha} = e^{i aL} * e^{i aHQ[s]}
// -> 2 trans for (cosL,sinL) + 2 trans in lanes 0..15 for the 16 slot phasors
// (broadcast via 32 readlanes to SGPRs) + 6 VALU per slot (angle-addition).
// Per-wave trans: 38 -> 10. Everything else = best-measured R10 structure.
// Prediction: if trans-rate theory right, kernel 38->~31us, dur_us ~77-80;
// if neutral, trans is quarter-rate and the plateau is declared next round.
//
// Layout (validated R4/R5): one wave per state; lane holds 16 complex amps,
// slots s = h*4+q, idx = h*256 + lane*4 + q.
//   slot bit0=wire9, bit1=wire8, bit2=wire1, bit3=wire0  (in-register gates)
//   lane bit l = wire 7-l                                 (cross-lane gates)
// Measurement partner idx^0x300 = slot^12 (in-register, no shuffles).
// Cross-lane masks 1,2,4,8 via DPP (VALU); 16,32 via permlane_swap (VALU).
// Scalar form (R10: cycle-neutral vs v_pk, DPP fusable into v_fmac_f32).

typedef unsigned int v2u __attribute__((ext_vector_type(2)));

template <int CTRL>
__device__ __forceinline__ float dppf(float x) {
    return __int_as_float(__builtin_amdgcn_update_dpp(
        __float_as_int(x), __float_as_int(x), CTRL, 0xF, 0xF, true));
}

template <int MASK>
__device__ __forceinline__ float lxor(float x) {
    if constexpr (MASK == 1)  return dppf<0xB1>(x);                   // quad_perm [1,0,3,2]
    else if constexpr (MASK == 2)  return dppf<0x4E>(x);              // quad_perm [2,3,0,1]
    else if constexpr (MASK == 4)  return dppf<0x141>(dppf<0x1B>(x)); // half_mirror o xor3
    else if constexpr (MASK == 8)  return dppf<0x128>(x);             // row_ror:8
    else if constexpr (MASK == 16)
        return __int_as_float(__builtin_amdgcn_ds_swizzle(__float_as_int(x), 0x401F));
    else return __shfl_xor(x, MASK, 64);
}

// partner value x[lane^MASK]; hi = (lane & MASK) != 0 (only used for 16/32)
template <int MASK>
__device__ __forceinline__ float xpartner(float x, bool hi) {
    if constexpr (MASK == 16) {
#if __has_builtin(__builtin_amdgcn_permlane16_swap)
        v2u r = __builtin_amdgcn_permlane16_swap(__float_as_uint(x), __float_as_uint(x),
                                                 false, false);
        return __uint_as_float(hi ? r.x : r.y);
#else
        (void)hi;
        return lxor<16>(x);
#endif
    } else if constexpr (MASK == 32) {
#if __has_builtin(__builtin_amdgcn_permlane32_swap)
        v2u r = __builtin_amdgcn_permlane32_swap(__float_as_uint(x), __float_as_uint(x),
                                                 false, false);
        return __uint_as_float(hi ? r.x : r.y);
#else
        (void)hi;
        return lxor<32>(x);
#endif
    } else {
        (void)hi;
        return lxor<MASK>(x);
    }
}

#define RLF(v, l) __int_as_float(__builtin_amdgcn_readlane(__float_as_int(v), (l)))

// RY pair rotation, scalar: a0' = c*a0 - s*a1 ; a1' = c*a1 + s*a0
__device__ __forceinline__ void rgate(float (&ax)[16], float (&ay)[16],
                                      int bit, float c, float s) {
#pragma unroll
    for (int s0 = 0; s0 < 16; s0++) {
        if (s0 & bit) continue;
        int s1 = s0 | bit;
        float a0x = ax[s0], a1x = ax[s1];
        float a0y = ay[s0], a1y = ay[s1];
        ax[s0] = __builtin_fmaf(-s, a1x, c * a0x);
        ax[s1] = __builtin_fmaf( s, a0x, c * a1x);
        ay[s0] = __builtin_fmaf(-s, a1y, c * a0y);
        ay[s1] = __builtin_fmaf( s, a0y, c * a1y);
    }
}

// cross-lane RY: a' = c*a + ss*partner(a), v_fmac-friendly form
template <int MASK>
__device__ __forceinline__ void xgate(float (&ax)[16], float (&ay)[16],
                                      float c, float ss, bool hi) {
#pragma unroll
    for (int r = 0; r < 16; r++) {
        float px = xpartner<MASK>(ax[r], hi);
        float py = xpartner<MASK>(ay[r], hi);
        float tx = c * ax[r];
        float ty = c * ay[r];
        ax[r] = __builtin_fmaf(px, ss, tx);
        ay[r] = __builtin_fmaf(py, ss, ty);
    }
}

__global__ __launch_bounds__(256, 8) void qk_sim(const float* __restrict__ x,
                                                 const float* __restrict__ w,
                                                 float* __restrict__ out,
                                                 int nstates) {
    int wave = (int)((blockIdx.x * blockDim.x + threadIdx.x) >> 6);
    int lane = threadIdx.x & 63;

    // ---- issue the 4 state loads FIRST (latency hides under prologue) ----
    const float4* rowx = (const float4*)(x + (size_t)wave * 1024);
    float4 vv0 = rowx[0 * 64 + lane];
    float4 vv1 = rowx[1 * 64 + lane];
    float4 vv2 = rowx[2 * 64 + lane];
    float4 vv3 = rowx[3 * 64 + lane];

    // ---- theta cos/sin: lanes 0..9 compute, broadcast via v_readlane ----
    int wi = (lane < 10) ? lane : 0;
    float thh = 0.5f * w[3 * wi + 1];
    float vc = __cosf(thh), vs = __sinf(thh);
    float c0 = RLF(vc, 0), s0 = RLF(vs, 0);
    float c1 = RLF(vc, 1), s1 = RLF(vs, 1);
    float c2 = RLF(vc, 2), s2 = RLF(vs, 2);
    float c3 = RLF(vc, 3), s3 = RLF(vs, 3);
    float c4 = RLF(vc, 4), s4 = RLF(vs, 4);
    float c5 = RLF(vc, 5), s5 = RLF(vs, 5);
    float c6 = RLF(vc, 6), s6 = RLF(vs, 6);
    float c7 = RLF(vc, 7), s7 = RLF(vs, 7);
    float c8 = RLF(vc, 8), s8 = RLF(vs, 8);
    float c9 = RLF(vc, 9), s9 = RLF(vs, 9);

    // ---- omega fold (uniform): d0 = w0+w1 omegas (h=0), d1 = w0-w1 (h=1) ----
    float om0 = w[2], om1 = w[5];
    float cD0 = __cosf(om0 + om1), sD0 = __sinf(om0 + om1);
    float cD1 = __cosf(om0 - om1), sD1 = __sinf(om0 - om1);

    // ---- phase angles: alpha(idx) = aL(lane) + aHQ(slot) ----
    // lane bit l -> wire 7-l (phi = w[3*(7-l)]); slot s = h*4+q:
    // h bit1->wire0 (pH), h bit0->wire1 (pHb); q bit1->wire8 (pQ), q bit0->wire9 (pQb)
    float aL = 0.f;
    if (lane & 1)  aL += w[21];
    if (lane & 2)  aL += w[18];
    if (lane & 4)  aL += w[15];
    if (lane & 8)  aL += w[12];
    if (lane & 16) aL += w[9];
    if (lane & 32) aL += w[6];
    float pH = w[0], pHb = w[3];   // wire0, wire1
    float pQ = w[24], pQb = w[27]; // wire8, wire9

    // per-lane phasor of aL (2 trans)
    float cL = __cosf(aL), sL = __sinf(aL);

    // 16 lane-uniform slot phasors: lanes 0..15 compute, broadcast (2 trans)
    int sl = lane & 15;
    float ahq = ((sl & 8) ? pH : 0.f) + ((sl & 4) ? pHb : 0.f)
              + ((sl & 2) ? pQ : 0.f) + ((sl & 1) ? pQb : 0.f);
    float vchq = __cosf(ahq), vshq = __sinf(ahq);
    float cHQ[16], sHQ[16];
#pragma unroll
    for (int s = 0; s < 16; s++) {
        cHQ[s] = RLF(vchq, s);
        sHQ[s] = RLF(vshq, s);
    }

    // ---- D_phi via angle addition: zero trans in the per-slot loop ----
    // cos(aL+aHQ) = cL*cHQ - sL*sHQ ; sin(aL+aHQ) = cL*sHQ + sL*cHQ
    float ax[16], ay[16];
#pragma unroll
    for (int h = 0; h < 4; h++) {
        const float4& v = (h == 0) ? vv0 : (h == 1) ? vv1 : (h == 2) ? vv2 : vv3;
        float xv[4] = {v.x, v.y, v.z, v.w};
#pragma unroll
        for (int q = 0; q < 4; q++) {
            int s = h * 4 + q;
            float u = __builtin_fmaf(-sL, sHQ[s], cL * cHQ[s]);
            float t = __builtin_fmaf( sL, cHQ[s], cL * sHQ[s]);
            ax[s] = xv[q] * u;
            ay[s] = xv[q] * t;
        }
    }

    // ---- in-register RY: slot bit0=wire9, bit1=wire8, bit2=wire1, bit3=wire0 ----
    rgate(ax, ay, 1, c9, s9);
    rgate(ax, ay, 2, c8, s8);
    rgate(ax, ay, 4, c1, s1);
    rgate(ax, ay, 8, c0, s0);

    // ---- cross-lane RY: lane bit l -> wire 7-l ----
    bool h16 = (lane & 16) != 0;
    bool h32 = (lane & 32) != 0;
    xgate<1> (ax, ay, c7, (lane & 1) ? s7 : -s7, false);
    xgate<2> (ax, ay, c6, (lane & 2) ? s6 : -s6, false);
    xgate<4> (ax, ay, c5, (lane & 4) ? s5 : -s5, false);
    xgate<8> (ax, ay, c4, (lane & 8) ? s4 : -s4, false);
    xgate<16>(ax, ay, c3, h16 ? s3 : -s3, h16);
    xgate<32>(ax, ay, c2, h32 ? s2 : -s2, h32);

    // ---- measurement: CNOT ring + D_omega folded; partner = slot^12 ----
    float ex2 = 0.f, ey2 = 0.f, ez0 = 0.f;
#pragma unroll
    for (int h = 0; h < 2; h++) {
        float cD = h ? cD1 : cD0;
        float sD = h ? sD1 : sD0;
#pragma unroll
        for (int q = 0; q < 4; q++) {
            int s  = h * 4 + q;
            int sp = s ^ 12;
            float mx = ax[s],  my = ay[s];
            float px = ax[sp], py = ay[sp];
            float cr = __builtin_fmaf(mx, px, my * py);    // Re(conj(m)*p)
            float ci = __builtin_fmaf(mx, py, -(my * px)); // Im(conj(m)*p)
            ex2 = __builtin_fmaf(cD, cr, ex2);
            ex2 = __builtin_fmaf(-sD, ci, ex2);
            float t = __builtin_fmaf(cD, ci, sD * cr);
            if ((h ^ (__popc(q) & 1)) & 1) ey2 -= t; else ey2 += t;
        }
    }
#pragma unroll
    for (int s = 0; s < 16; s++) {
        float n = __builtin_fmaf(ax[s], ax[s], ay[s] * ay[s]);
        if ((((s >> 2) & 1) ^ (__popc(s & 3) & 1)) & 1) ez0 -= n; else ez0 += n;
    }
    float psgn = (__popc(lane) & 1) ? -1.f : 1.f;
    float ex = 2.f * ex2;
    float ey = 2.f * psgn * ey2;
    float ez = psgn * ez0;

    // ---- wave reduction: DPP for 1,2,4,8; permlane_swap for 16,32 ----
#define RED(M, HI) { ex += xpartner<M>(ex, HI); ey += xpartner<M>(ey, HI); \
                     ez += xpartner<M>(ez, HI); }
    RED(1, false) RED(2, false) RED(4, false) RED(8, false) RED(16, h16) RED(32, h32)
#undef RED

    if (lane == 0) {
        float* o = out + 3 * (size_t)wave;
        o[0] = ex; o[1] = ey; o[2] = ez;
    }
}

extern "C" void kernel_launch(void* const* d_in, const int* in_sizes, int n_in,
                              void* d_out, int out_size, void* d_ws, size_t ws_size,
                              hipStream_t stream) {
    const float* patch   = (const float*)d_in[0];
    const float* weights = (const float*)d_in[1];
    float* out = (float*)d_out;

    int nstates = in_sizes[0] / 1024;  // 8192

    int nblocks = nstates / 4;  // 4 waves (256 threads) per block, grid exact
    qk_sim<<<nblocks, 256, 0, stream>>>(patch, weights, out, nstates);
}